// Round 17
// baseline (47.403 us; speedup 1.0000x reference)
//
#include <hip/hip_runtime.h>

typedef float v2f __attribute__((ext_vector_type(2)));
typedef __fp16 h2 __attribute__((ext_vector_type(2)));
typedef unsigned int u32;

constexpr int BN   = 131072;   // points
constexpr int HID  = 20;       // hidden width
constexpr int NLAY = 7;        // hidden->hidden layers

// LDS layout for slow path (floats)
constexpr int OFF_WH   = 0;      // 7*20*20 = 2800
constexpr int OFF_BH   = 2800;   // 7*20    = 140
constexpr int OFF_WIN  = 2940;   // 3*20    = 60
constexpr int OFF_BIN  = 3000;   // 20
constexpr int OFF_WOUT = 3020;   // 20*2    = 40
constexpr int OFF_BOUT = 3060;   // 2
constexpr int LDS_TOT  = 3064;

// ws slots (slow path only)
enum { S_PX = 0, S_PXX, S_PXXX, S_P, S_GPX,
       S_PY, S_PYY, S_PYYY, S_GPY,
       S_D2P, S_D3P, S_D3M, S_XT, S_YT, NSLOT };

__device__ __forceinline__ float fast_tanh(float a) {
    float e = __builtin_amdgcn_exp2f(a * 2.8853900817779268f);
    float r = __builtin_amdgcn_rcpf(e + 1.0f);
    return __builtin_fmaf(-2.0f, r, 1.0f);
}
__device__ __forceinline__ v2f tanh2(v2f a) {
    v2f r; r.x = fast_tanh(a.x); r.y = fast_tanh(a.y); return r;
}
__device__ __forceinline__ v2f splat(float s) { v2f r = {s, s}; return r; }
#define FMA2(a, b, c) __builtin_elementwise_fma((a), (b), (c))

union h2u { u32 u; h2 h; };
__device__ __forceinline__ h2 pk2(float lo, float hi) {
    return __builtin_amdgcn_cvt_pkrtz(lo, hi);
}
__device__ __forceinline__ h2 bith2(u32 w) { h2u t; t.u = w; return t.h; }
__device__ __forceinline__ float dot2(h2 a, h2 b, float c) {
#if __has_builtin(__builtin_amdgcn_fdot2)
    return __builtin_amdgcn_fdot2(a, b, c, false);
#else
    return __builtin_fmaf((float)a.y, (float)b.y,
           __builtin_fmaf((float)a.x, (float)b.x, c));
#endif
}

// acc(2 outs) += S.lo * w(2 outs)   (slow path)
__device__ __forceinline__ void pk_fma_lo(v2f& acc, const v2f s, const v2f w) {
    asm("v_pk_fma_f32 %0, %1, %2, %0 op_sel:[0,0,0] op_sel_hi:[0,1,1]"
        : "+v"(acc) : "v"(s), "v"(w));
}
__device__ __forceinline__ void pk_fma_hi(v2f& acc, const v2f s, const v2f w) {
    asm("v_pk_fma_f32 %0, %1, %2, %0 op_sel:[1,0,0] op_sel_hi:[1,1,1]"
        : "+v"(acc) : "v"(s), "v"(w));
}

__device__ __forceinline__ void stage_weights(
    float* smem, const float* Win, const float* bin, const float* Wh,
    const float* bh, const float* Wout, const float* bout)
{
    const int tid = threadIdx.x;
    for (int i = tid; i < 2800; i += 256) smem[OFF_WH + i] = Wh[i];
    for (int i = tid; i < 140;  i += 256) smem[OFF_BH + i] = bh[i];
    if (tid < 60) smem[OFF_WIN  + tid] = Win[tid];
    if (tid < 20) smem[OFF_BIN  + tid] = bin[tid];
    if (tid < 40) smem[OFF_WOUT + tid] = Wout[tid];
    if (tid < 2)  smem[OFF_BOUT + tid] = bout[tid];
    __syncthreads();
}

// Two-channel matvec sweep (slow path): A1 = W^T S1 (+bias), A2 = W^T S2.
template<bool BIASED>
__device__ __forceinline__ void sweep2(const v2f (&S1)[10], const v2f (&S2)[10],
                                       v2f (&A1)[10], v2f (&A2)[10],
                                       const float* __restrict__ Wl,
                                       const float* __restrict__ bl)
{
    #pragma unroll
    for (int j = 0; j < 10; ++j) {
        if (BIASED) { A1[j].x = bl[2*j]; A1[j].y = bl[2*j+1]; }
        else        A1[j] = splat(0.f);
        A2[j] = splat(0.f);
    }
    #pragma unroll
    for (int i = 0; i < 10; ++i) {
        const float* r0 = &Wl[(2 * i) * HID];
        const float* r1 = &Wl[(2 * i + 1) * HID];
        #pragma unroll
        for (int ob = 0; ob < 5; ++ob) {
            float4 w0 = *(const float4*)&r0[4 * ob];
            float4 w1 = *(const float4*)&r1[4 * ob];
            v2f w0a = {w0.x, w0.y}, w0b = {w0.z, w0.w};
            v2f w1a = {w1.x, w1.y}, w1b = {w1.z, w1.w};
            pk_fma_lo(A1[2*ob],   S1[i], w0a);
            pk_fma_lo(A1[2*ob+1], S1[i], w0b);
            pk_fma_hi(A1[2*ob],   S1[i], w1a);
            pk_fma_hi(A1[2*ob+1], S1[i], w1b);
            pk_fma_lo(A2[2*ob],   S2[i], w0a);
            pk_fma_lo(A2[2*ob+1], S2[i], w0b);
            pk_fma_hi(A2[2*ob],   S2[i], w1a);
            pk_fma_hi(A2[2*ob+1], S2[i], w1b);
        }
    }
}

// ---------------------------------------------------------------- MERGED KERNEL
// blockIdx.y == 0: fast path (lambda == 0) — f16 weight pairs + f16 state,
//                  v_dot2_f32_f16 matvec, half the LDS bytes per layer.
// blockIdx.y == 1..6: slow-path jet slices (lambda != 0), fp32 exact.
__global__ __launch_bounds__(256)
__attribute__((amdgpu_waves_per_eu(2, 2)))
void pinn_main(
    const float* __restrict__ x, const float* __restrict__ y, const float* __restrict__ t,
    const float* __restrict__ u, const float* __restrict__ v,
    const float* __restrict__ Win, const float* __restrict__ bin,
    const float* __restrict__ Wh,  const float* __restrict__ bh,
    const float* __restrict__ Wout,const float* __restrict__ bout,
    const float* __restrict__ lam1p, const float* __restrict__ lam2p,
    float* __restrict__ ws, float* __restrict__ out)
{
    const bool lam0 = (lam1p[0] == 0.0f && lam2p[0] == 0.0f);
    if (blockIdx.y == 0) { if (!lam0) return; }
    else                 { if (lam0)  return; }

    __shared__ __align__(16) float smem[LDS_TOT];          // slow path
    __shared__ __align__(16) u32   wpk[NLAY * 200];        // fast: f16 weight pairs
    __shared__ __align__(16) float sB[NLAY * 20];          // fast: biases fp32
    __shared__ float sIn[60], sBin[20], sWo[40], sBo[2];
    __shared__ float wsum[4];

    const int tid = threadIdx.x;
    const int pt  = blockIdx.x * 256 + tid;

    // early global loads (overlap the staging barrier)
    const float xv = x[pt], yv = y[pt], tv = t[pt];

    if (blockIdx.y == 0) {
        // ======================= FAST PATH =======================
        const float uv = u[pt], vv = v[pt];

        // stage: f16 pair (w[2ip][o], w[2ip+1][o]) at wpk[l*200 + ip*20 + o]
        for (int idx = tid; idx < NLAY * 200; idx += 256) {
            const int l = idx / 200, r = idx % 200;
            const int ip = r / 20, o = r % 20;
            const float wa = Wh[l * 400 + (2 * ip) * 20 + o];
            const float wb = Wh[l * 400 + (2 * ip + 1) * 20 + o];
            h2u tpk; tpk.h = pk2(wa, wb);
            wpk[idx] = tpk.u;
        }
        for (int i = tid; i < NLAY * 20; i += 256) sB[i] = bh[i];
        if (tid < 60) sIn[tid] = Win[tid];
        if (tid < 20) sBin[tid] = bin[tid];
        if (tid < 40) sWo[tid]  = Wout[tid];
        if (tid < 2)  sBo[tid]  = bout[tid];
        __syncthreads();

        // ---- input layer (fp32 exact, then pack to f16 pairs)
        h2 stV[10], stX[10], stY[10];
        #pragma unroll
        for (int j = 0; j < 10; ++j) {
            float sv[2], sx[2], sy[2];
            #pragma unroll
            for (int hh = 0; hh < 2; ++hh) {
                const int n = 2 * j + hh;
                const float w0 = sIn[n], w1 = sIn[20 + n], w2 = sIn[40 + n];
                const float a = __builtin_fmaf(tv, w2,
                                 __builtin_fmaf(yv, w1,
                                  __builtin_fmaf(xv, w0, sBin[n])));
                const float s  = fast_tanh(a);
                const float s1 = 1.0f - s * s;
                sv[hh] = s; sx[hh] = s1 * w0; sy[hh] = s1 * w1;
            }
            stV[j] = pk2(sv[0], sv[1]);
            stX[j] = pk2(sx[0], sx[1]);
            stY[j] = pk2(sy[0], sy[1]);
        }

        // ---- hidden layers (pipelined weight-row loads, f16 dot2 matvec)
        uint4 WR[5];
        #pragma unroll
        for (int q = 0; q < 5; ++q) WR[q] = *(const uint4*)&wpk[4 * q];

        #pragma unroll 1
        for (int l = 0; l < NLAY; ++l) {
            const u32* Wl = &wpk[l * 200];
            const u32* Wn = &wpk[((l == NLAY - 1) ? l : l + 1) * 200];

            float aV[20], aX[20], aY[20];
            #pragma unroll
            for (int q = 0; q < 5; ++q) {
                float4 B = *(const float4*)&sB[l * 20 + 4 * q];
                aV[4*q+0] = B.x; aV[4*q+1] = B.y; aV[4*q+2] = B.z; aV[4*q+3] = B.w;
                aX[4*q+0] = 0.f; aX[4*q+1] = 0.f; aX[4*q+2] = 0.f; aX[4*q+3] = 0.f;
                aY[4*q+0] = 0.f; aY[4*q+1] = 0.f; aY[4*q+2] = 0.f; aY[4*q+3] = 0.f;
            }

            #pragma unroll
            for (int ip = 0; ip < 10; ++ip) {
                // prefetch next row (ip==9 -> next layer's row 0, hides under mixing)
                uint4 NR[5];
                const u32* nr = (ip < 9) ? &Wl[(ip + 1) * 20] : &Wn[0];
                #pragma unroll
                for (int q = 0; q < 5; ++q) NR[q] = *(const uint4*)&nr[4 * q];

                const h2 sv = stV[ip], sx = stX[ip], sy = stY[ip];
                #pragma unroll
                for (int q = 0; q < 5; ++q) {
                    const h2 w0 = bith2(WR[q].x), w1 = bith2(WR[q].y),
                             w2 = bith2(WR[q].z), w3 = bith2(WR[q].w);
                    aV[4*q+0] = dot2(sv, w0, aV[4*q+0]);
                    aX[4*q+0] = dot2(sx, w0, aX[4*q+0]);
                    aY[4*q+0] = dot2(sy, w0, aY[4*q+0]);
                    aV[4*q+1] = dot2(sv, w1, aV[4*q+1]);
                    aX[4*q+1] = dot2(sx, w1, aX[4*q+1]);
                    aY[4*q+1] = dot2(sy, w1, aY[4*q+1]);
                    aV[4*q+2] = dot2(sv, w2, aV[4*q+2]);
                    aX[4*q+2] = dot2(sx, w2, aX[4*q+2]);
                    aY[4*q+2] = dot2(sy, w2, aY[4*q+2]);
                    aV[4*q+3] = dot2(sv, w3, aV[4*q+3]);
                    aX[4*q+3] = dot2(sx, w3, aX[4*q+3]);
                    aY[4*q+3] = dot2(sy, w3, aY[4*q+3]);
                }
                #pragma unroll
                for (int q = 0; q < 5; ++q) WR[q] = NR[q];
            }

            // mixing (fp32 tanh, repack to f16 pairs)
            #pragma unroll
            for (int j = 0; j < 10; ++j) {
                const float s0  = fast_tanh(aV[2*j]);
                const float s1a = 1.0f - s0 * s0;
                const float sb  = fast_tanh(aV[2*j+1]);
                const float s1b = 1.0f - sb * sb;
                stV[j] = pk2(s0, sb);
                stX[j] = pk2(s1a * aX[2*j], s1b * aX[2*j+1]);
                stY[j] = pk2(s1a * aY[2*j], s1b * aY[2*j+1]);
            }
        }

        // ---- output layer (fp32): col0 -> psi, col1 -> p
        float dX = 0.f, dY = 0.f, dP = 0.f, dPX = 0.f, dPY = 0.f;
        #pragma unroll
        for (int j = 0; j < 10; ++j) {
            const float V0 = (float)stV[j].x, V1 = (float)stV[j].y;
            const float X0 = (float)stX[j].x, X1 = (float)stX[j].y;
            const float Y0 = (float)stY[j].x, Y1 = (float)stY[j].y;
            const int n0 = 2 * j, n1 = 2 * j + 1;
            dX  = __builtin_fmaf(X0, sWo[2*n0],   __builtin_fmaf(X1, sWo[2*n1],   dX));
            dY  = __builtin_fmaf(Y0, sWo[2*n0],   __builtin_fmaf(Y1, sWo[2*n1],   dY));
            dP  = __builtin_fmaf(V0, sWo[2*n0+1], __builtin_fmaf(V1, sWo[2*n1+1], dP));
            dPX = __builtin_fmaf(X0, sWo[2*n0+1], __builtin_fmaf(X1, sWo[2*n1+1], dPX));
            dPY = __builtin_fmaf(Y0, sWo[2*n0+1], __builtin_fmaf(Y1, sWo[2*n1+1], dPY));
        }
        const float pv = sBo[1] + dP;

        out[3*pt+0] = pv;        // p
        out[3*pt+1] = dY;        // u_pred = psi_y
        out[3*pt+2] = -dX;       // v_pred = -psi_x

        const float du = uv - dY;
        const float dv = vv + dX;
        // lambda1 = lambda2 = 0 => f_u = p_x, f_v = p_y
        float term = du * du + dv * dv + dPX * dPX + dPY * dPY;

        #pragma unroll
        for (int off = 32; off > 0; off >>= 1) term += __shfl_down(term, off);
        const int lane = tid & 63, wid = tid >> 6;
        if (lane == 0) wsum[wid] = term;
        __syncthreads();
        if (tid == 0) atomicAdd(&out[3*BN], wsum[0] + wsum[1] + wsum[2] + wsum[3]);
        return;
    }

    // ======================= SLOW PATH (lambda != 0, fp32 exact) =======================
    stage_weights(smem, Win, bin, Wh, bh, Wout, bout);

    const int slice = blockIdx.y - 1;
    const v2f xv2 = splat(xv), yv2 = splat(yv), tv2 = splat(tv);

    if (slice < 4) {
        const float DXT[4] = {1.f, 0.f, 1.f,  1.f};
        const float DYT[4] = {0.f, 1.f, 1.f, -1.f};
        const v2f dxv = splat(DXT[slice]), dyv = splat(DYT[slice]);

        v2f V[10], D1[10], D2[10], D3[10];

        #pragma unroll
        for (int j = 0; j < 10; ++j) {
            v2f w0 = *(const v2f*)&smem[OFF_WIN + 2*j];
            v2f w1 = *(const v2f*)&smem[OFF_WIN + HID + 2*j];
            v2f w2 = *(const v2f*)&smem[OFF_WIN + 2*HID + 2*j];
            v2f av = *(const v2f*)&smem[OFF_BIN + 2*j];
            av = FMA2(xv2, w0, av);
            av = FMA2(yv2, w1, av);
            av = FMA2(tv2, w2, av);
            v2f a1 = dxv * w0;
            a1 = FMA2(dyv, w1, a1);
            v2f s  = tanh2(av);
            v2f s2 = s * s;
            v2f s1 = 1.0f - s2;
            v2f f2 = -2.0f * s * s1;
            v2f f3 = s1 * (4.0f * s2 - 2.0f * s1);
            v2f a1sq = a1 * a1;
            V[j]  = s;
            D1[j] = s1 * a1;
            D2[j] = f2 * a1sq;
            D3[j] = f3 * a1sq * a1;
        }

        #pragma unroll 1
        for (int l = 0; l < NLAY; ++l) {
            const float* Wl = &smem[OFF_WH + l * (HID * HID)];
            const float* bl = &smem[OFF_BH + l * HID];
            v2f aV[10], a1[10];
            sweep2<true >(V,  D1, aV, a1, Wl, bl);
            v2f a2[10], a3[10];
            sweep2<false>(D2, D3, a2, a3, Wl, bl);
            #pragma unroll
            for (int j = 0; j < 10; ++j) {
                v2f s  = tanh2(aV[j]);
                v2f s2 = s * s;
                v2f s1 = 1.0f - s2;
                v2f f2 = -2.0f * s * s1;
                v2f f3 = s1 * (4.0f * s2 - 2.0f * s1);
                v2f u1 = a1[j];
                v2f u1sq = u1 * u1;
                V[j]  = s;
                D1[j] = s1 * u1;
                D2[j] = s1 * a2[j] + f2 * u1sq;
                D3[j] = s1 * a3[j] + 3.0f * f2 * (u1 * a2[j]) + f3 * u1sq * u1;
            }
        }

        v2f d1 = splat(0.f), d2 = splat(0.f), d3 = splat(0.f),
            dP = splat(0.f), dP1 = splat(0.f);
        #pragma unroll
        for (int j = 0; j < 10; ++j) {
            v2f w0j = {smem[OFF_WOUT + 4*j],     smem[OFF_WOUT + 4*j + 2]};
            v2f w1j = {smem[OFF_WOUT + 4*j + 1], smem[OFF_WOUT + 4*j + 3]};
            d1  = FMA2(D1[j], w0j, d1);
            d2  = FMA2(D2[j], w0j, d2);
            d3  = FMA2(D3[j], w0j, d3);
            dP  = FMA2(V[j],  w1j, dP);
            dP1 = FMA2(D1[j], w1j, dP1);
        }
        const float r1 = d1.x + d1.y;
        const float r2 = d2.x + d2.y;
        const float r3 = d3.x + d3.y;

        switch (slice) {
            case 0:
                ws[S_PX  *BN+pt] = r1;
                ws[S_PXX *BN+pt] = r2;
                ws[S_PXXX*BN+pt] = r3;
                ws[S_P   *BN+pt] = smem[OFF_BOUT + 1] + dP.x + dP.y;
                ws[S_GPX *BN+pt] = dP1.x + dP1.y;
                break;
            case 1:
                ws[S_PY  *BN+pt] = r1;
                ws[S_PYY *BN+pt] = r2;
                ws[S_PYYY*BN+pt] = r3;
                ws[S_GPY *BN+pt] = dP1.x + dP1.y;
                break;
            case 2:
                ws[S_D2P *BN+pt] = r2;
                ws[S_D3P *BN+pt] = r3;
                break;
            default:
                ws[S_D3M *BN+pt] = r3;
                break;
        }
    } else {
        v2f V[10], DA[10], DT[10], DAT[10];

        #pragma unroll
        for (int j = 0; j < 10; ++j) {
            v2f w0 = *(const v2f*)&smem[OFF_WIN + 2*j];
            v2f w1 = *(const v2f*)&smem[OFF_WIN + HID + 2*j];
            v2f w2 = *(const v2f*)&smem[OFF_WIN + 2*HID + 2*j];
            v2f av = *(const v2f*)&smem[OFF_BIN + 2*j];
            av = FMA2(xv2, w0, av);
            av = FMA2(yv2, w1, av);
            av = FMA2(tv2, w2, av);
            v2f wa = (slice == 4) ? w0 : w1;
            v2f s  = tanh2(av);
            v2f s1 = 1.0f - s * s;
            v2f f2 = -2.0f * s * s1;
            V[j]   = s;
            DA[j]  = s1 * wa;
            DT[j]  = s1 * w2;
            DAT[j] = f2 * wa * w2;
        }

        #pragma unroll 1
        for (int l = 0; l < NLAY; ++l) {
            const float* Wl = &smem[OFF_WH + l * (HID * HID)];
            const float* bl = &smem[OFF_BH + l * HID];
            v2f aV[10], aA[10];
            sweep2<true >(V,  DA,  aV, aA, Wl, bl);
            v2f aT[10], aAT[10];
            sweep2<false>(DT, DAT, aT, aAT, Wl, bl);
            #pragma unroll
            for (int j = 0; j < 10; ++j) {
                v2f s  = tanh2(aV[j]);
                v2f s1 = 1.0f - s * s;
                v2f f2 = -2.0f * s * s1;
                V[j]   = s;
                DA[j]  = s1 * aA[j];
                DT[j]  = s1 * aT[j];
                DAT[j] = f2 * (aA[j] * aT[j]) + s1 * aAT[j];
            }
        }

        v2f dAT = splat(0.f);
        #pragma unroll
        for (int j = 0; j < 10; ++j) {
            v2f w0j = {smem[OFF_WOUT + 4*j], smem[OFF_WOUT + 4*j + 2]};
            dAT = FMA2(DAT[j], w0j, dAT);
        }
        const float r = dAT.x + dAT.y;
        if (slice == 4) ws[S_XT*BN+pt] = r;
        else            ws[S_YT*BN+pt] = r;
    }
}

// ---------------------------------------------------------------- SLOW PATH combine
__global__ __launch_bounds__(256) void pinn_combine(
    const float* __restrict__ ws,
    const float* __restrict__ u, const float* __restrict__ v,
    const float* __restrict__ lam1p, const float* __restrict__ lam2p,
    float* __restrict__ out)
{
    if (lam1p[0] == 0.0f && lam2p[0] == 0.0f) return;   // fast path covers

    __shared__ float wsum[4];
    const int tid = threadIdx.x;
    const int pt  = blockIdx.x * 256 + tid;

    const float psi_x   = ws[S_PX  *BN+pt];
    const float psi_xx  = ws[S_PXX *BN+pt];
    const float psi_xxx = ws[S_PXXX*BN+pt];
    const float pv      = ws[S_P   *BN+pt];
    const float p_x     = ws[S_GPX *BN+pt];
    const float psi_y   = ws[S_PY  *BN+pt];
    const float psi_yy  = ws[S_PYY *BN+pt];
    const float psi_yyy = ws[S_PYYY*BN+pt];
    const float p_y     = ws[S_GPY *BN+pt];
    const float d2p     = ws[S_D2P *BN+pt];
    const float d3p     = ws[S_D3P *BN+pt];
    const float d3m     = ws[S_D3M *BN+pt];
    const float psi_xt  = ws[S_XT  *BN+pt];
    const float psi_yt  = ws[S_YT  *BN+pt];

    const float psi_xy  = 0.5f * (d2p - psi_xx - psi_yy);
    const float psi_xxy = (d3p - d3m - 2.0f * psi_yyy) * (1.0f / 6.0f);
    const float psi_xyy = (d3p + d3m - 2.0f * psi_xxx) * (1.0f / 6.0f);

    const float u_pred = psi_y;
    const float v_pred = -psi_x;
    const float u_x = psi_xy,  u_y = psi_yy,  u_t = psi_yt;
    const float v_x = -psi_xx, v_y = -psi_xy, v_t = -psi_xt;
    const float u_xx = psi_xxy, u_yy = psi_yyy;
    const float v_xx = -psi_xxx, v_yy = -psi_xyy;

    const float lam1 = lam1p[0];
    const float lam2 = lam2p[0];

    const float f_u = lam1 * (u_t + u_pred * u_x + v_pred * u_y) + p_x - lam2 * (u_xx + u_yy);
    const float f_v = lam1 * (v_t + u_pred * v_x + v_pred * v_y) - lam1 * 9.81f + p_y
                      - lam2 * (v_xx + v_yy);

    out[3*pt+0] = pv;
    out[3*pt+1] = u_pred;
    out[3*pt+2] = v_pred;

    const float du = u[pt] - u_pred;
    const float dv = v[pt] - v_pred;
    float term = du * du + dv * dv + f_u * f_u + f_v * f_v;

    #pragma unroll
    for (int off = 32; off > 0; off >>= 1) term += __shfl_down(term, off);
    const int lane = tid & 63, wid = tid >> 6;
    if (lane == 0) wsum[wid] = term;
    __syncthreads();
    if (tid == 0) atomicAdd(&out[3*BN], wsum[0] + wsum[1] + wsum[2] + wsum[3]);
}

extern "C" void kernel_launch(void* const* d_in, const int* in_sizes, int n_in,
                              void* d_out, int out_size, void* d_ws, size_t ws_size,
                              hipStream_t stream) {
    const float* x    = (const float*)d_in[0];
    const float* y    = (const float*)d_in[1];
    const float* t    = (const float*)d_in[2];
    const float* u    = (const float*)d_in[3];
    const float* v    = (const float*)d_in[4];
    const float* Win  = (const float*)d_in[5];
    const float* bin  = (const float*)d_in[6];
    const float* Wh   = (const float*)d_in[7];
    const float* bh   = (const float*)d_in[8];
    const float* Wout = (const float*)d_in[9];
    const float* bout = (const float*)d_in[10];
    const float* lam1 = (const float*)d_in[11];
    const float* lam2 = (const float*)d_in[12];

    float* out = (float*)d_out;
    float* ws  = (float*)d_ws;

    (void)hipMemsetAsync(out + 3 * BN, 0, sizeof(float), stream);

    // merged: y=0 fast path (lambda==0), y=1..6 slow-path jet slices (lambda!=0)
    pinn_main<<<dim3(BN / 256, 7), 256, 0, stream>>>(x, y, t, u, v, Win, bin, Wh, bh,
                                                     Wout, bout, lam1, lam2, ws, out);
    pinn_combine<<<BN / 256, 256, 0, stream>>>(ws, u, v, lam1, lam2, out);
}

// Round 18
// 43.402 us; speedup vs baseline: 1.0922x; 1.0922x over previous
//
#include <hip/hip_runtime.h>

typedef float v2f __attribute__((ext_vector_type(2)));

constexpr int BN   = 131072;   // points
constexpr int HID  = 20;       // hidden width
constexpr int NLAY = 7;        // hidden->hidden layers

// LDS layout (floats)
constexpr int OFF_WH   = 0;      // 7*20*20 = 2800
constexpr int OFF_BH   = 2800;   // 7*20    = 140
constexpr int OFF_WIN  = 2940;   // 3*20    = 60
constexpr int OFF_BIN  = 3000;   // 20
constexpr int OFF_WOUT = 3020;   // 20*2    = 40
constexpr int OFF_BOUT = 3060;   // 2
constexpr int LDS_TOT  = 3064;

// ws slots (slow path only)
enum { S_PX = 0, S_PXX, S_PXXX, S_P, S_GPX,
       S_PY, S_PYY, S_PYYY, S_GPY,
       S_D2P, S_D3P, S_D3M, S_XT, S_YT, NSLOT };

__device__ __forceinline__ float fast_tanh(float a) {
    float e = __builtin_amdgcn_exp2f(a * 2.8853900817779268f);
    float r = __builtin_amdgcn_rcpf(e + 1.0f);
    return __builtin_fmaf(-2.0f, r, 1.0f);
}
__device__ __forceinline__ v2f tanh2(v2f a) {
    v2f r; r.x = fast_tanh(a.x); r.y = fast_tanh(a.y); return r;
}
__device__ __forceinline__ v2f splat(float s) { v2f r = {s, s}; return r; }
#define FMA2(a, b, c) __builtin_elementwise_fma((a), (b), (c))

// acc(2 outs) += S.lo * w(2 outs)
__device__ __forceinline__ void pk_fma_lo(v2f& acc, const v2f s, const v2f w) {
    asm("v_pk_fma_f32 %0, %1, %2, %0 op_sel:[0,0,0] op_sel_hi:[0,1,1]"
        : "+v"(acc) : "v"(s), "v"(w));
}
// acc(2 outs) += S.hi * w(2 outs)
__device__ __forceinline__ void pk_fma_hi(v2f& acc, const v2f s, const v2f w) {
    asm("v_pk_fma_f32 %0, %1, %2, %0 op_sel:[1,0,0] op_sel_hi:[1,1,1]"
        : "+v"(acc) : "v"(s), "v"(w));
}

__device__ __forceinline__ void stage_weights(
    float* smem, const float* Win, const float* bin, const float* Wh,
    const float* bh, const float* Wout, const float* bout)
{
    const int tid = threadIdx.x;
    for (int i = tid; i < 2800; i += 256) smem[OFF_WH + i] = Wh[i];
    for (int i = tid; i < 140;  i += 256) smem[OFF_BH + i] = bh[i];
    if (tid < 60) smem[OFF_WIN  + tid] = Win[tid];
    if (tid < 20) smem[OFF_BIN  + tid] = bin[tid];
    if (tid < 40) smem[OFF_WOUT + tid] = Wout[tid];
    if (tid < 2)  smem[OFF_BOUT + tid] = bout[tid];
    __syncthreads();
}

// Two-channel matvec sweep (slow path): A1 = W^T S1 (+bias), A2 = W^T S2.
template<bool BIASED>
__device__ __forceinline__ void sweep2(const v2f (&S1)[10], const v2f (&S2)[10],
                                       v2f (&A1)[10], v2f (&A2)[10],
                                       const float* __restrict__ Wl,
                                       const float* __restrict__ bl)
{
    #pragma unroll
    for (int j = 0; j < 10; ++j) {
        if (BIASED) { A1[j].x = bl[2*j]; A1[j].y = bl[2*j+1]; }
        else        A1[j] = splat(0.f);
        A2[j] = splat(0.f);
    }
    #pragma unroll
    for (int i = 0; i < 10; ++i) {
        const float* r0 = &Wl[(2 * i) * HID];
        const float* r1 = &Wl[(2 * i + 1) * HID];
        #pragma unroll
        for (int ob = 0; ob < 5; ++ob) {
            float4 w0 = *(const float4*)&r0[4 * ob];
            float4 w1 = *(const float4*)&r1[4 * ob];
            v2f w0a = {w0.x, w0.y}, w0b = {w0.z, w0.w};
            v2f w1a = {w1.x, w1.y}, w1b = {w1.z, w1.w};
            pk_fma_lo(A1[2*ob],   S1[i], w0a);
            pk_fma_lo(A1[2*ob+1], S1[i], w0b);
            pk_fma_hi(A1[2*ob],   S1[i], w1a);
            pk_fma_hi(A1[2*ob+1], S1[i], w1b);
            pk_fma_lo(A2[2*ob],   S2[i], w0a);
            pk_fma_lo(A2[2*ob+1], S2[i], w0b);
            pk_fma_hi(A2[2*ob],   S2[i], w1a);
            pk_fma_hi(A2[2*ob+1], S2[i], w1b);
        }
    }
}

// ---------------------------------------------------------------- MERGED KERNEL
// blockIdx.y == 0: fast path (lambda == 0), cross-layer-pipelined 3-channel jet.
// blockIdx.y == 1..6: slow-path jet slices (lambda != 0).
__global__ __launch_bounds__(256)
__attribute__((amdgpu_waves_per_eu(2, 2)))
void pinn_main(
    const float* __restrict__ x, const float* __restrict__ y, const float* __restrict__ t,
    const float* __restrict__ u, const float* __restrict__ v,
    const float* __restrict__ Win, const float* __restrict__ bin,
    const float* __restrict__ Wh,  const float* __restrict__ bh,
    const float* __restrict__ Wout,const float* __restrict__ bout,
    const float* __restrict__ lam1p, const float* __restrict__ lam2p,
    float* __restrict__ ws, float* __restrict__ out)
{
    const bool lam0 = (lam1p[0] == 0.0f && lam2p[0] == 0.0f);
    if (blockIdx.y == 0) { if (!lam0) return; }
    else                 { if (lam0)  return; }

    __shared__ __align__(16) float smem[LDS_TOT];
    __shared__ float wsum[4];

    const int tid = threadIdx.x;
    const int pt  = blockIdx.x * 256 + tid;

    // early global loads (overlap the staging barrier)
    const float xv = x[pt], yv = y[pt], tv = t[pt];
    float uv = 0.f, vv = 0.f;
    if (blockIdx.y == 0) { uv = u[pt]; vv = v[pt]; }

    stage_weights(smem, Win, bin, Wh, bh, Wout, bout);

    const v2f xv2 = splat(xv), yv2 = splat(yv), tv2 = splat(tv);

    if (blockIdx.y == 0) {
        // ======================= FAST PATH =======================
        v2f V[10], DX[10], DY[10];

        #pragma unroll
        for (int j = 0; j < 10; ++j) {
            v2f w0 = *(const v2f*)&smem[OFF_WIN + 2*j];
            v2f w1 = *(const v2f*)&smem[OFF_WIN + HID + 2*j];
            v2f w2 = *(const v2f*)&smem[OFF_WIN + 2*HID + 2*j];
            v2f av = *(const v2f*)&smem[OFF_BIN + 2*j];
            av = FMA2(xv2, w0, av);
            av = FMA2(yv2, w1, av);
            av = FMA2(tv2, w2, av);
            v2f s  = tanh2(av);
            v2f s1 = 1.0f - s * s;
            V[j]  = s;
            DX[j] = s1 * w0;
            DY[j] = s1 * w1;
        }

        // peel: preload layer 0 rows 0,1 (these loads overlap the input layer)
        float4 WE[5], WO[5];
        #pragma unroll
        for (int q = 0; q < 5; ++q) {
            WE[q] = *(const float4*)&smem[OFF_WH + 4 * q];
            WO[q] = *(const float4*)&smem[OFF_WH + HID + 4 * q];
        }

        #pragma unroll 1
        for (int l = 0; l < NLAY; ++l) {
            const float* Wl    = &smem[OFF_WH + l * 400];
            const float* Wnext = &smem[OFF_WH + ((l == NLAY - 1) ? l : l + 1) * 400];
            const float* bl    = &smem[OFF_BH + l * HID];

            v2f aV[10], aX[10], aY[10];
            #pragma unroll
            for (int j = 0; j < 10; ++j) {
                aV[j].x = bl[2*j]; aV[j].y = bl[2*j+1];
                aX[j] = splat(0.f);
                aY[j] = splat(0.f);
            }

            #pragma unroll
            for (int i = 0; i < 10; ++i) {
                // prefetch: i<9 -> this layer's next row pair;
                //           i==9 -> NEXT layer's rows 0,1 (hide under mixing)
                float4 NE[5], NO[5];
                const float* n0 = (i < 9) ? &Wl[(2 * i + 2) * HID] : &Wnext[0];
                const float* n1 = (i < 9) ? &Wl[(2 * i + 3) * HID] : &Wnext[HID];
                #pragma unroll
                for (int q = 0; q < 5; ++q) {
                    NE[q] = *(const float4*)&n0[4 * q];
                    NO[q] = *(const float4*)&n1[4 * q];
                }
                #pragma unroll
                for (int ob = 0; ob < 5; ++ob) {
                    v2f w0a = {WE[ob].x, WE[ob].y}, w0b = {WE[ob].z, WE[ob].w};
                    v2f w1a = {WO[ob].x, WO[ob].y}, w1b = {WO[ob].z, WO[ob].w};
                    pk_fma_lo(aV[2*ob],   V[i],  w0a);
                    pk_fma_lo(aV[2*ob+1], V[i],  w0b);
                    pk_fma_hi(aV[2*ob],   V[i],  w1a);
                    pk_fma_hi(aV[2*ob+1], V[i],  w1b);
                    pk_fma_lo(aX[2*ob],   DX[i], w0a);
                    pk_fma_lo(aX[2*ob+1], DX[i], w0b);
                    pk_fma_hi(aX[2*ob],   DX[i], w1a);
                    pk_fma_hi(aX[2*ob+1], DX[i], w1b);
                    pk_fma_lo(aY[2*ob],   DY[i], w0a);
                    pk_fma_lo(aY[2*ob+1], DY[i], w0b);
                    pk_fma_hi(aY[2*ob],   DY[i], w1a);
                    pk_fma_hi(aY[2*ob+1], DY[i], w1b);
                }
                #pragma unroll
                for (int q = 0; q < 5; ++q) { WE[q] = NE[q]; WO[q] = NO[q]; }
            }

            // mixing phase runs with next layer's rows 0,1 already in flight
            #pragma unroll
            for (int j = 0; j < 10; ++j) {
                v2f s  = tanh2(aV[j]);
                v2f s1 = 1.0f - s * s;
                V[j]  = s;
                DX[j] = s1 * aX[j];
                DY[j] = s1 * aY[j];
            }
        }

        // output layer: col0 -> psi, col1 -> p
        v2f dX = splat(0.f), dY = splat(0.f), dP = splat(0.f),
            dPX = splat(0.f), dPY = splat(0.f);
        #pragma unroll
        for (int j = 0; j < 10; ++j) {
            v2f w0j = {smem[OFF_WOUT + 4*j],     smem[OFF_WOUT + 4*j + 2]};
            v2f w1j = {smem[OFF_WOUT + 4*j + 1], smem[OFF_WOUT + 4*j + 3]};
            dX  = FMA2(DX[j], w0j, dX);
            dY  = FMA2(DY[j], w0j, dY);
            dP  = FMA2(V[j],  w1j, dP);
            dPX = FMA2(DX[j], w1j, dPX);
            dPY = FMA2(DY[j], w1j, dPY);
        }
        const float psi_x = dX.x + dX.y;
        const float psi_y = dY.x + dY.y;
        const float pv    = smem[OFF_BOUT + 1] + dP.x + dP.y;
        const float p_x   = dPX.x + dPX.y;
        const float p_y   = dPY.x + dPY.y;

        out[3*pt+0] = pv;
        out[3*pt+1] = psi_y;      // u_pred
        out[3*pt+2] = -psi_x;     // v_pred

        const float du = uv - psi_y;
        const float dv = vv + psi_x;
        // lambda1 = lambda2 = 0 => f_u = p_x, f_v = p_y
        float term = du * du + dv * dv + p_x * p_x + p_y * p_y;

        #pragma unroll
        for (int off = 32; off > 0; off >>= 1) term += __shfl_down(term, off);
        const int lane = tid & 63, wid = tid >> 6;
        if (lane == 0) wsum[wid] = term;
        __syncthreads();
        if (tid == 0) atomicAdd(&out[3*BN], wsum[0] + wsum[1] + wsum[2] + wsum[3]);
        return;
    }

    // ======================= SLOW PATH (lambda != 0) =======================
    const int slice = blockIdx.y - 1;

    if (slice < 4) {
        const float DXT[4] = {1.f, 0.f, 1.f,  1.f};
        const float DYT[4] = {0.f, 1.f, 1.f, -1.f};
        const v2f dxv = splat(DXT[slice]), dyv = splat(DYT[slice]);

        v2f V[10], D1[10], D2[10], D3[10];

        #pragma unroll
        for (int j = 0; j < 10; ++j) {
            v2f w0 = *(const v2f*)&smem[OFF_WIN + 2*j];
            v2f w1 = *(const v2f*)&smem[OFF_WIN + HID + 2*j];
            v2f w2 = *(const v2f*)&smem[OFF_WIN + 2*HID + 2*j];
            v2f av = *(const v2f*)&smem[OFF_BIN + 2*j];
            av = FMA2(xv2, w0, av);
            av = FMA2(yv2, w1, av);
            av = FMA2(tv2, w2, av);
            v2f a1 = dxv * w0;
            a1 = FMA2(dyv, w1, a1);
            v2f s  = tanh2(av);
            v2f s2 = s * s;
            v2f s1 = 1.0f - s2;
            v2f f2 = -2.0f * s * s1;
            v2f f3 = s1 * (4.0f * s2 - 2.0f * s1);
            v2f a1sq = a1 * a1;
            V[j]  = s;
            D1[j] = s1 * a1;
            D2[j] = f2 * a1sq;
            D3[j] = f3 * a1sq * a1;
        }

        #pragma unroll 1
        for (int l = 0; l < NLAY; ++l) {
            const float* Wl = &smem[OFF_WH + l * (HID * HID)];
            const float* bl = &smem[OFF_BH + l * HID];
            v2f aV[10], a1[10];
            sweep2<true >(V,  D1, aV, a1, Wl, bl);
            v2f a2[10], a3[10];
            sweep2<false>(D2, D3, a2, a3, Wl, bl);
            #pragma unroll
            for (int j = 0; j < 10; ++j) {
                v2f s  = tanh2(aV[j]);
                v2f s2 = s * s;
                v2f s1 = 1.0f - s2;
                v2f f2 = -2.0f * s * s1;
                v2f f3 = s1 * (4.0f * s2 - 2.0f * s1);
                v2f u1 = a1[j];
                v2f u1sq = u1 * u1;
                V[j]  = s;
                D1[j] = s1 * u1;
                D2[j] = s1 * a2[j] + f2 * u1sq;
                D3[j] = s1 * a3[j] + 3.0f * f2 * (u1 * a2[j]) + f3 * u1sq * u1;
            }
        }

        v2f d1 = splat(0.f), d2 = splat(0.f), d3 = splat(0.f),
            dP = splat(0.f), dP1 = splat(0.f);
        #pragma unroll
        for (int j = 0; j < 10; ++j) {
            v2f w0j = {smem[OFF_WOUT + 4*j],     smem[OFF_WOUT + 4*j + 2]};
            v2f w1j = {smem[OFF_WOUT + 4*j + 1], smem[OFF_WOUT + 4*j + 3]};
            d1  = FMA2(D1[j], w0j, d1);
            d2  = FMA2(D2[j], w0j, d2);
            d3  = FMA2(D3[j], w0j, d3);
            dP  = FMA2(V[j],  w1j, dP);
            dP1 = FMA2(D1[j], w1j, dP1);
        }
        const float r1 = d1.x + d1.y;
        const float r2 = d2.x + d2.y;
        const float r3 = d3.x + d3.y;

        switch (slice) {
            case 0:
                ws[S_PX  *BN+pt] = r1;
                ws[S_PXX *BN+pt] = r2;
                ws[S_PXXX*BN+pt] = r3;
                ws[S_P   *BN+pt] = smem[OFF_BOUT + 1] + dP.x + dP.y;
                ws[S_GPX *BN+pt] = dP1.x + dP1.y;
                break;
            case 1:
                ws[S_PY  *BN+pt] = r1;
                ws[S_PYY *BN+pt] = r2;
                ws[S_PYYY*BN+pt] = r3;
                ws[S_GPY *BN+pt] = dP1.x + dP1.y;
                break;
            case 2:
                ws[S_D2P *BN+pt] = r2;
                ws[S_D3P *BN+pt] = r3;
                break;
            default:
                ws[S_D3M *BN+pt] = r3;
                break;
        }
    } else {
        v2f V[10], DA[10], DT[10], DAT[10];

        #pragma unroll
        for (int j = 0; j < 10; ++j) {
            v2f w0 = *(const v2f*)&smem[OFF_WIN + 2*j];
            v2f w1 = *(const v2f*)&smem[OFF_WIN + HID + 2*j];
            v2f w2 = *(const v2f*)&smem[OFF_WIN + 2*HID + 2*j];
            v2f av = *(const v2f*)&smem[OFF_BIN + 2*j];
            av = FMA2(xv2, w0, av);
            av = FMA2(yv2, w1, av);
            av = FMA2(tv2, w2, av);
            v2f wa = (slice == 4) ? w0 : w1;
            v2f s  = tanh2(av);
            v2f s1 = 1.0f - s * s;
            v2f f2 = -2.0f * s * s1;
            V[j]   = s;
            DA[j]  = s1 * wa;
            DT[j]  = s1 * w2;
            DAT[j] = f2 * wa * w2;
        }

        #pragma unroll 1
        for (int l = 0; l < NLAY; ++l) {
            const float* Wl = &smem[OFF_WH + l * (HID * HID)];
            const float* bl = &smem[OFF_BH + l * HID];
            v2f aV[10], aA[10];
            sweep2<true >(V,  DA,  aV, aA, Wl, bl);
            v2f aT[10], aAT[10];
            sweep2<false>(DT, DAT, aT, aAT, Wl, bl);
            #pragma unroll
            for (int j = 0; j < 10; ++j) {
                v2f s  = tanh2(aV[j]);
                v2f s1 = 1.0f - s * s;
                v2f f2 = -2.0f * s * s1;
                V[j]   = s;
                DA[j]  = s1 * aA[j];
                DT[j]  = s1 * aT[j];
                DAT[j] = f2 * (aA[j] * aT[j]) + s1 * aAT[j];
            }
        }

        v2f dAT = splat(0.f);
        #pragma unroll
        for (int j = 0; j < 10; ++j) {
            v2f w0j = {smem[OFF_WOUT + 4*j], smem[OFF_WOUT + 4*j + 2]};
            dAT = FMA2(DAT[j], w0j, dAT);
        }
        const float r = dAT.x + dAT.y;
        if (slice == 4) ws[S_XT*BN+pt] = r;
        else            ws[S_YT*BN+pt] = r;
    }
}

// ---------------------------------------------------------------- SLOW PATH combine
__global__ __launch_bounds__(256) void pinn_combine(
    const float* __restrict__ ws,
    const float* __restrict__ u, const float* __restrict__ v,
    const float* __restrict__ lam1p, const float* __restrict__ lam2p,
    float* __restrict__ out)
{
    if (lam1p[0] == 0.0f && lam2p[0] == 0.0f) return;   // fast path covers

    __shared__ float wsum[4];
    const int tid = threadIdx.x;
    const int pt  = blockIdx.x * 256 + tid;

    const float psi_x   = ws[S_PX  *BN+pt];
    const float psi_xx  = ws[S_PXX *BN+pt];
    const float psi_xxx = ws[S_PXXX*BN+pt];
    const float pv      = ws[S_P   *BN+pt];
    const float p_x     = ws[S_GPX *BN+pt];
    const float psi_y   = ws[S_PY  *BN+pt];
    const float psi_yy  = ws[S_PYY *BN+pt];
    const float psi_yyy = ws[S_PYYY*BN+pt];
    const float p_y     = ws[S_GPY *BN+pt];
    const float d2p     = ws[S_D2P *BN+pt];
    const float d3p     = ws[S_D3P *BN+pt];
    const float d3m     = ws[S_D3M *BN+pt];
    const float psi_xt  = ws[S_XT  *BN+pt];
    const float psi_yt  = ws[S_YT  *BN+pt];

    const float psi_xy  = 0.5f * (d2p - psi_xx - psi_yy);
    const float psi_xxy = (d3p - d3m - 2.0f * psi_yyy) * (1.0f / 6.0f);
    const float psi_xyy = (d3p + d3m - 2.0f * psi_xxx) * (1.0f / 6.0f);

    const float u_pred = psi_y;
    const float v_pred = -psi_x;
    const float u_x = psi_xy,  u_y = psi_yy,  u_t = psi_yt;
    const float v_x = -psi_xx, v_y = -psi_xy, v_t = -psi_xt;
    const float u_xx = psi_xxy, u_yy = psi_yyy;
    const float v_xx = -psi_xxx, v_yy = -psi_xyy;

    const float lam1 = lam1p[0];
    const float lam2 = lam2p[0];

    const float f_u = lam1 * (u_t + u_pred * u_x + v_pred * u_y) + p_x - lam2 * (u_xx + u_yy);
    const float f_v = lam1 * (v_t + u_pred * v_x + v_pred * v_y) - lam1 * 9.81f + p_y
                      - lam2 * (v_xx + v_yy);

    out[3*pt+0] = pv;
    out[3*pt+1] = u_pred;
    out[3*pt+2] = v_pred;

    const float du = u[pt] - u_pred;
    const float dv = v[pt] - v_pred;
    float term = du * du + dv * dv + f_u * f_u + f_v * f_v;

    #pragma unroll
    for (int off = 32; off > 0; off >>= 1) term += __shfl_down(term, off);
    const int lane = tid & 63, wid = tid >> 6;
    if (lane == 0) wsum[wid] = term;
    __syncthreads();
    if (tid == 0) atomicAdd(&out[3*BN], wsum[0] + wsum[1] + wsum[2] + wsum[3]);
}

extern "C" void kernel_launch(void* const* d_in, const int* in_sizes, int n_in,
                              void* d_out, int out_size, void* d_ws, size_t ws_size,
                              hipStream_t stream) {
    const float* x    = (const float*)d_in[0];
    const float* y    = (const float*)d_in[1];
    const float* t    = (const float*)d_in[2];
    const float* u    = (const float*)d_in[3];
    const float* v    = (const float*)d_in[4];
    const float* Win  = (const float*)d_in[5];
    const float* bin  = (const float*)d_in[6];
    const float* Wh   = (const float*)d_in[7];
    const float* bh   = (const float*)d_in[8];
    const float* Wout = (const float*)d_in[9];
    const float* bout = (const float*)d_in[10];
    const float* lam1 = (const float*)d_in[11];
    const float* lam2 = (const float*)d_in[12];

    float* out = (float*)d_out;
    float* ws  = (float*)d_ws;

    (void)hipMemsetAsync(out + 3 * BN, 0, sizeof(float), stream);

    // merged: y=0 fast path (lambda==0), y=1..6 slow-path jet slices (lambda!=0)
    pinn_main<<<dim3(BN / 256, 7), 256, 0, stream>>>(x, y, t, u, v, Win, bin, Wh, bh,
                                                     Wout, bout, lam1, lam2, ws, out);
    pinn_combine<<<BN / 256, 256, 0, stream>>>(ws, u, v, lam1, lam2, out);
}